// Round 8
// baseline (1326.387 us; speedup 1.0000x reference)
//
#include <hip/hip_runtime.h>
#include <cstdint>
#include <cstddef>

#define T_   10
#define B_   128
#define CH_  512
#define N_   16
#define H_   16
#define HID_ 2048
#define TB_  (T_ * B_)       // 1280 (t,b) slabs

// Epilogue modes
#define EP_QKV  0   // scatter u8 spikes to qs/ks/vs in scan layout
#define EP_U8   1   // u8 spikes, normal (T,B,C,N) layout (sproj)
#define EP_HS   2   // u8 spikes, T-layout [slab*16+n][2048] (hsT)
#define EP_OUT  3   // fp32 out = x + sproj + spike

typedef __attribute__((ext_vector_type(8))) short bf16x8;
typedef __attribute__((ext_vector_type(4))) float f32x4;

__device__ __forceinline__ short f2b(float f) {      // fp32 -> bf16 bits, RNE
    uint32_t u = __float_as_uint(f);
    return (short)((u + 0x7FFFu + ((u >> 16) & 1u)) >> 16);
}
__device__ __forceinline__ float b2f(short s) {
    return __uint_as_float(((uint32_t)(uint16_t)s) << 16);
}

// ---------------------------------------------------------------------------
// Fold BN (+opt conv bias) into weights; emit bf16 hi/lo, [m][K] k-contig.
// ---------------------------------------------------------------------------
__global__ void fold2(const float* __restrict__ W, const float* __restrict__ bnp,
                      const float* __restrict__ eb, int M, int K, int o0,
                      short* __restrict__ Ah, short* __restrict__ Al,
                      float* __restrict__ bias) {
    int idx = blockIdx.x * 256 + threadIdx.x;
    if (idx >= M * K) return;
    int o = idx / K, k = idx - o * K;
    float g  = bnp[o];
    float be = bnp[M + o];
    float mu = bnp[2 * M + o];
    float va = bnp[3 * M + o];
    float inv = g * (1.0f / sqrtf(va + 1e-5f));
    float w = W[idx] * inv;
    short h = f2b(w);
    Ah[(size_t)(o0 + o) * K + k] = h;
    Al[(size_t)(o0 + o) * K + k] = f2b(w - b2f(h));
    if (k == 0) bias[o0 + o] = ((eb ? eb[o] : 0.0f) - mu) * inv + be;
}

// ---------------------------------------------------------------------------
// Pack activations to T-layout bf16 hi/lo:
//   in : X (T,B,C,N) fp32 [+ optional u8 spike add]
//   out: HT/LT [slab*16 + n][C]  (k-contiguous rows, MFMA-frag ready)
// One block per slab; LDS transpose with +1-per-32 skew (conflict ~2-way).
// ---------------------------------------------------------------------------
__global__ __launch_bounds__(256) void packT(
    const float* __restrict__ X, const uint8_t* __restrict__ S,
    short* __restrict__ HT, short* __restrict__ LT) {
    __shared__ float xs[8448];   // 8192 + 256 skew
    const int slab = blockIdx.x;
    const float* xp = X + (size_t)slab * 8192;
    const uint8_t* sp = S ? S + (size_t)slab * 8192 : nullptr;
    for (int i = threadIdx.x; i < 8192; i += 256) {
        float v = xp[i];
        if (sp) v += (float)sp[i];
        xs[i + (i >> 5)] = v;
    }
    __syncthreads();
    const int n = threadIdx.x >> 4;        // 0..15
    const int c2b = threadIdx.x & 15;
    unsigned int* Hp = (unsigned int*)(HT + ((size_t)slab * 16 + n) * 512);
    unsigned int* Lp = (unsigned int*)(LT + ((size_t)slab * 16 + n) * 512);
#pragma unroll
    for (int j = 0; j < 16; ++j) {
        int c2 = c2b + 16 * j;             // uint index; c = 2*c2
        int i0 = (2 * c2) * 16 + n, i1 = (2 * c2 + 1) * 16 + n;
        float v0 = xs[i0 + (i0 >> 5)];
        float v1 = xs[i1 + (i1 >> 5)];
        short h0 = f2b(v0), h1 = f2b(v1);
        short l0 = f2b(v0 - b2f(h0)), l1 = f2b(v1 - b2f(h1));
        Hp[c2] = (unsigned int)(uint16_t)h0 | ((unsigned int)(uint16_t)h1 << 16);
        Lp[c2] = (unsigned int)(uint16_t)l0 | ((unsigned int)(uint16_t)l1 << 16);
    }
}

// ---------------------------------------------------------------------------
// Barrier-free MFMA GEMM + fused LIF. No LDS: B-fragments are loaded directly
// from T-layout global (row = slab*16+n, k-contiguous) as dwordx4; A (bf16
// hi/lo, [m][K]) likewise. Wave: R 16-row tiles x 16 tokens x all 10 t accs.
// Split precision: BU8 (spikes, exact): Ah*B + Al*B.  NP=3: + Ah*Bl.
// Grid: blockIdx.x = b (fastest -> same-b row-tiles share an XCD/L2),
//       blockIdx.y = row-tile of R*64 rows.  NOTE: gridDim.y * R * 64 == M.
// ---------------------------------------------------------------------------
template <int R, int NP, int BU8, int EPI>
__global__ __launch_bounds__(256, 3) void gemm2(
    const short* __restrict__ Ah, const short* __restrict__ Al,
    const float* __restrict__ bias,
    const short* __restrict__ BhT, const short* __restrict__ BlT,
    const uint8_t* __restrict__ BuT,
    uint8_t* __restrict__ O0, uint8_t* __restrict__ O1, uint8_t* __restrict__ O2,
    float* __restrict__ Oout, const float* __restrict__ Xr,
    const uint8_t* __restrict__ Sr, int K) {
    const int lane = threadIdx.x & 63;
    const int wv   = threadIdx.x >> 6;
    const int b    = blockIdx.x;
    const int l15  = lane & 15;
    const int q    = lane >> 4;
    const int row0 = blockIdx.y * (R * 64) + wv * (R * 16);

    f32x4 acc[R][10];
#pragma unroll
    for (int r = 0; r < R; ++r)
#pragma unroll
        for (int t = 0; t < 10; ++t) acc[r][t] = 0.0f;

    for (int k0 = 0; k0 < K; k0 += 32) {
        bf16x8 ah[R], al[R];
#pragma unroll
        for (int r = 0; r < R; ++r) {
            size_t ga = (size_t)(row0 + r * 16 + l15) * K + k0 + q * 8;
            ah[r] = *(const bf16x8*)&Ah[ga];
            al[r] = *(const bf16x8*)&Al[ga];
        }
#pragma unroll
        for (int t = 0; t < 10; ++t) {
            const size_t gb = ((size_t)(t * B_ + b) * 16 + l15) * K + k0 + q * 8;
            bf16x8 bh, bl;
            if constexpr (BU8) {
                uint2 w = *(const uint2*)&BuT[gb];
                union { short s[8]; bf16x8 v; } bb;
#pragma unroll
                for (int j = 0; j < 4; ++j) {
                    bb.s[j]     = ((w.x >> (8 * j)) & 255u) ? (short)0x3F80 : (short)0;
                    bb.s[4 + j] = ((w.y >> (8 * j)) & 255u) ? (short)0x3F80 : (short)0;
                }
                bh = bb.v;
            } else {
                bh = *(const bf16x8*)&BhT[gb];
                if constexpr (NP == 3) bl = *(const bf16x8*)&BlT[gb];
            }
#pragma unroll
            for (int r = 0; r < R; ++r) {
                acc[r][t] = __builtin_amdgcn_mfma_f32_16x16x32_bf16(ah[r], bh, acc[r][t], 0, 0, 0);
                acc[r][t] = __builtin_amdgcn_mfma_f32_16x16x32_bf16(al[r], bh, acc[r][t], 0, 0, 0);
                if constexpr (NP == 3)
                    acc[r][t] = __builtin_amdgcn_mfma_f32_16x16x32_bf16(ah[r], bl, acc[r][t], 0, 0, 0);
            }
        }
    }

    // ---- epilogue: lane holds (row = q*4+reg, tok = l15) x all 10 t ----
    const int tok = l15;
#pragma unroll
    for (int r = 0; r < R; ++r) {
#pragma unroll
        for (int reg = 0; reg < 4; ++reg) {
            const int row = row0 + r * 16 + q * 4 + reg;
            const float bsv = bias[row];
            int tsr = row >> 9;
            int c   = row & 511;
            int hh  = (c & 31) >> 1;
            int dd  = ((c & 1) << 4) | tok;
            int nn  = c >> 5;
            uint8_t* qp = (tsr == 0) ? O0 : ((tsr == 1) ? O1 : O2);
            size_t qoff = (size_t)hh * 512 + dd * 16 + nn;
            float mem = 0.0f;
#pragma unroll
            for (int t = 0; t < 10; ++t) {
                float u = acc[r][t][reg] + bsv;
                mem += (u - mem) * 0.5f;
                bool s = mem > 1.0f;
                if (s) mem = 0.0f;
                if constexpr (EPI == EP_QKV) {
                    qp[(size_t)(t * B_ + b) * 8192 + qoff] = (uint8_t)s;
                } else if constexpr (EPI == EP_U8) {
                    O0[(size_t)(t * B_ + b) * 8192 + (size_t)row * 16 + tok] = (uint8_t)s;
                } else if constexpr (EPI == EP_HS) {
                    O0[((size_t)(t * B_ + b) * 16 + tok) * 2048 + row] = (uint8_t)s;
                } else {  // EP_OUT
                    size_t off = (size_t)(t * B_ + b) * 8192 + (size_t)row * 16 + tok;
                    Oout[off] = Xr[off] + (float)Sr[off] + (s ? 1.0f : 0.0f);
                }
            }
        }
    }
}

// ---------------------------------------------------------------------------
// Wave-synchronous temporal scan (unchanged, known-good): one wave per
// (b,h), zero barriers; ti_w in registers; skewed/padded LDS.
// ---------------------------------------------------------------------------
__global__ __launch_bounds__(64, 2) void scan_kernel(
    const uint8_t* __restrict__ qs, const uint8_t* __restrict__ ks,
    const uint8_t* __restrict__ vs, const float* __restrict__ tiw,
    const float* __restrict__ tib, uint8_t* __restrict__ y1T) {
    __shared__ float qS[36 * 20];   // [d+2][n] spike carry, halo rows = 0
    __shared__ float kS[32 * 20];
    __shared__ float vS[32 * 20];
    __shared__ float qbS[32 * 20];
    __shared__ float A[16 * 17];
    const int l  = threadIdx.x;
    const int bh = blockIdx.x;
    const int b  = bh >> 4, h = bh & 15;
    const int n  = l & 15, dg = l >> 4;

    float wreg[80];
#pragma unroll
    for (int j = 0; j < 80; ++j) wreg[j] = tiw[n * 80 + j];
    const float tibr = tib[n];

    if (l < 40) { qS[l] = 0.0f; qS[680 + l] = 0.0f; }

    {
        size_t base = (size_t)b * 8192 + (size_t)h * 512;
        unsigned long long qw = *(const unsigned long long*)&qs[base + l * 8];
        unsigned long long kw = *(const unsigned long long*)&ks[base + l * 8];
        unsigned long long vw = *(const unsigned long long*)&vs[base + l * 8];
#pragma unroll
        for (int j = 0; j < 8; ++j) {
            int f = l * 8 + j, d = f >> 4, m = f & 15;
            qS[(d + 2) * 20 + m] = (float)((qw >> (8 * j)) & 255);
            kS[d * 20 + m]       = (float)((kw >> (8 * j)) & 255);
            vS[d * 20 + m]       = (float)((vw >> (8 * j)) & 255);
        }
    }

    float mem1[8] = {}, mem2[8] = {}, mem3[8] = {};

    auto attn_step = [&](int t) {
        float dots[4] = {0.0f, 0.0f, 0.0f, 0.0f};
#pragma unroll
        for (int d = 0; d < 32; ++d) {
            float qv = qS[(d + 2) * 20 + n];
#pragma unroll
            for (int jj = 0; jj < 4; ++jj)
                dots[jj] = fmaf(qv, kS[d * 20 + dg * 4 + jj], dots[jj]);
        }
#pragma unroll
        for (int jj = 0; jj < 4; ++jj) A[n * 17 + dg * 4 + jj] = dots[jj] * 0.25f;
        float o[8] = {};
#pragma unroll
        for (int m = 0; m < 16; ++m) {
            float av = A[n * 17 + m];
#pragma unroll
            for (int dd = 0; dd < 8; ++dd)
                o[dd] = fmaf(av, vS[(dg * 8 + dd) * 20 + m], o[dd]);
        }
        unsigned long long yw = 0;
#pragma unroll
        for (int dd = 0; dd < 8; ++dd) {
            mem3[dd] += (o[dd] - mem3[dd]) * 0.5f;
            bool s3 = mem3[dd] > 1.0f;
            if (s3) mem3[dd] = 0.0f;
            yw |= ((unsigned long long)(s3 ? 1u : 0u)) << (8 * dd);
        }
        *(unsigned long long*)
            &y1T[((size_t)(t * B_ + b) * 16 + n) * 512 + h * 32 + dg * 8] = yw;
    };

    attn_step(0);

    for (int t = 1; t < T_; ++t) {
        size_t base = (size_t)(t * B_ + b) * 8192 + (size_t)h * 512;
        unsigned long long qw = *(const unsigned long long*)&qs[base + l * 8];
        unsigned long long kw = *(const unsigned long long*)&ks[base + l * 8];
        unsigned long long vw = *(const unsigned long long*)&vs[base + l * 8];
#pragma unroll
        for (int j = 0; j < 8; ++j) {
            int f = l * 8 + j, d = f >> 4, m = f & 15;
            qbS[d * 20 + m] = (float)((qw >> (8 * j)) & 255);
            kS[d * 20 + m]  = (float)((kw >> (8 * j)) & 255);
            vS[d * 20 + m]  = (float)((vw >> (8 * j)) & 255);
        }
        float c[8];
#pragma unroll
        for (int dd = 0; dd < 8; ++dd) c[dd] = tibr;
#pragma unroll
        for (int x = 0; x < 12; ++x) {
            const float* rp = &qS[(dg * 8 + x) * 20];
            float qrow[16];
            *(float4*)&qrow[0]  = *(const float4*)&rp[0];
            *(float4*)&qrow[4]  = *(const float4*)&rp[4];
            *(float4*)&qrow[8]  = *(const float4*)&rp[8];
            *(float4*)&qrow[12] = *(const float4*)&rp[12];
            const int kmin = (x > 7) ? (x - 7) : 0;
            const int kmax = (x < 4) ? x : 4;
#pragma unroll
            for (int i = 0; i < 16; ++i)
#pragma unroll 5
                for (int k = kmin; k <= kmax; ++k)
                    c[x - k] = fmaf(wreg[i * 5 + k], qrow[i], c[x - k]);
        }
#pragma unroll
        for (int dd = 0; dd < 8; ++dd) {
            mem1[dd] += (c[dd] - mem1[dd]) * 0.5f;
            bool s1 = mem1[dd] > 1.0f;
            if (s1) mem1[dd] = 0.0f;
            float qb = qbS[(dg * 8 + dd) * 20 + n];
            float mix = 0.5f * (s1 ? 1.0f : 0.0f) + 0.5f * qb;
            mem2[dd] += (mix - mem2[dd]) * 0.5f;
            bool s2 = mem2[dd] > 1.0f;
            if (s2) mem2[dd] = 0.0f;
            qS[(dg * 8 + dd + 2) * 20 + n] = s2 ? 1.0f : 0.0f;
        }
        attn_step(t);
    }
}

// ---------------------------------------------------------------------------
extern "C" void kernel_launch(void* const* d_in, const int* in_sizes, int n_in,
                              void* d_out, int out_size, void* d_ws, size_t ws_size,
                              hipStream_t stream) {
    const float* x    = (const float*)d_in[0];
    const float* Wq   = (const float*)d_in[1];
    const float* Wk   = (const float*)d_in[2];
    const float* Wv   = (const float*)d_in[3];
    const float* Wp   = (const float*)d_in[4];
    const float* bnq  = (const float*)d_in[5];
    const float* bnk  = (const float*)d_in[6];
    const float* bnv  = (const float*)d_in[7];
    const float* bnpj = (const float*)d_in[8];
    const float* tiw  = (const float*)d_in[9];
    const float* tib  = (const float*)d_in[10];
    const float* W1   = (const float*)d_in[11];
    const float* b1   = (const float*)d_in[12];
    const float* bn1  = (const float*)d_in[13];
    const float* W2   = (const float*)d_in[14];
    const float* b2   = (const float*)d_in[15];
    const float* bn2  = (const float*)d_in[16];
    float* out = (float*)d_out;

    char* ws = (char*)d_ws;
    size_t cur = 0;
    auto alloc = [&](size_t bytes) -> void* {
        void* p = ws + cur;
        cur = (cur + bytes + 255) & ~(size_t)255;
        return p;
    };
    const size_t SL = (size_t)TB_ * 8192;      // 10.49M elems per u8 slab set
    uint8_t* hsT   = (uint8_t*)alloc(4 * SL);  // [slab*16+n][2048]; overlays qkv spikes
    uint8_t* qsb   = hsT;                      // scan-layout spikes (dead before hsT)
    uint8_t* ksb   = hsT + SL;
    uint8_t* vsb   = hsT + 2 * SL;
    uint8_t* y1T   = hsT + 3 * SL;             // T-layout spikes (dead before hsT)
    uint8_t* sproj = (uint8_t*)alloc(SL);
    short* xTh = (short*)alloc(SL * 2);        // T-layout x hi (reused for x+sproj)
    short* xTl = (short*)alloc(SL * 2);        // T-layout x lo
    short* Ah_qkv = (short*)alloc((size_t)1536 * 512 * 2);
    short* Al_qkv = (short*)alloc((size_t)1536 * 512 * 2);
    short* Ah_p   = (short*)alloc((size_t)512 * 512 * 2);
    short* Al_p   = (short*)alloc((size_t)512 * 512 * 2);
    short* Ah_1   = (short*)alloc((size_t)2048 * 512 * 2);
    short* Al_1   = (short*)alloc((size_t)2048 * 512 * 2);
    short* Ah_2   = (short*)alloc((size_t)512 * 2048 * 2);
    short* Al_2   = (short*)alloc((size_t)512 * 2048 * 2);
    float* bs_qkv = (float*)alloc(1536 * 4);
    float* bs_p   = (float*)alloc(512 * 4);
    float* bs_1   = (float*)alloc(2048 * 4);
    float* bs_2   = (float*)alloc(512 * 4);
    // total ~107 MB

    // --- prep: fold BN, split bf16 hi/lo, [m][K] ---
    fold2<<<1024, 256, 0, stream>>>(Wq, bnq, nullptr, 512, 512, 0,    Ah_qkv, Al_qkv, bs_qkv);
    fold2<<<1024, 256, 0, stream>>>(Wk, bnk, nullptr, 512, 512, 512,  Ah_qkv, Al_qkv, bs_qkv);
    fold2<<<1024, 256, 0, stream>>>(Wv, bnv, nullptr, 512, 512, 1024, Ah_qkv, Al_qkv, bs_qkv);
    fold2<<<1024, 256, 0, stream>>>(Wp, bnpj, nullptr, 512, 512, 0,   Ah_p, Al_p, bs_p);
    fold2<<<4096, 256, 0, stream>>>(W1, bn1, b1, 2048, 512, 0,        Ah_1, Al_1, bs_1);
    fold2<<<4096, 256, 0, stream>>>(W2, bn2, b2, 512, 2048, 0,        Ah_2, Al_2, bs_2);

    // --- SSA ---
    packT<<<TB_, 256, 0, stream>>>(x, nullptr, xTh, xTl);
    gemm2<2, 3, 0, EP_QKV><<<dim3(B_, 12), 256, 0, stream>>>(   // 12*128 = 1536 rows
        Ah_qkv, Al_qkv, bs_qkv, xTh, xTl, nullptr, qsb, ksb, vsb,
        nullptr, nullptr, nullptr, 512);
    scan_kernel<<<B_ * H_, 64, 0, stream>>>(qsb, ksb, vsb, tiw, tib, y1T);
    gemm2<2, 2, 1, EP_U8><<<dim3(B_, 4), 256, 0, stream>>>(     // 4*128 = 512 rows
        Ah_p, Al_p, bs_p, nullptr, nullptr, y1T, sproj, nullptr, nullptr,
        nullptr, nullptr, nullptr, 512);

    // --- MLP ---
    packT<<<TB_, 256, 0, stream>>>(x, sproj, xTh, xTl);   // x2 = x + sproj
    gemm2<2, 3, 0, EP_HS><<<dim3(B_, 16), 256, 0, stream>>>(    // 16*128 = 2048 rows
        Ah_1, Al_1, bs_1, xTh, xTl, nullptr, hsT, nullptr, nullptr,
        nullptr, nullptr, nullptr, 512);
    gemm2<2, 2, 1, EP_OUT><<<dim3(B_, 4), 256, 0, stream>>>(    // 4*128 = 512 rows
        Ah_2, Al_2, bs_2, nullptr, nullptr, hsT, nullptr, nullptr, nullptr,
        out, x, sproj, 2048);
}